// Round 3
// baseline (317.779 us; speedup 1.0000x reference)
//
#include <hip/hip_runtime.h>
#include <hip/hip_bf16.h>

// ---------------------------------------------------------------------------
// CollapsedPBFA: x->(qkv GEMM)->cheb-kernelized linear attention->out GEMM
// All matmuls via v_mfma_f32_16x16x32_bf16 (f32 accumulate).
// beta sparsity (only m=1..5 nonzero for the given inputs) exploited at
// runtime: zero-beta m-blocks exit / are skipped.
// ---------------------------------------------------------------------------

#define SEQ    4096
#define BATCH  2
#define DMODEL 1024
#define NH     16
#define DH     64
#define MD     11

typedef __attribute__((ext_vector_type(8)))  short  short8;
typedef __attribute__((ext_vector_type(8)))  __bf16 bf16x8;
typedef __attribute__((ext_vector_type(4)))  float  f32x4;

__device__ __forceinline__ short f2bf(float f) {
  union { float f; unsigned u; } c; c.f = f;
  unsigned r = c.u + 0x7FFFu + ((c.u >> 16) & 1u);
  return (short)(r >> 16);
}
__device__ __forceinline__ float bf2f(short h) {
  union { unsigned u; float f; } c; c.u = ((unsigned)(unsigned short)h) << 16;
  return c.f;
}

__device__ __forceinline__ f32x4 mfma16(short8 a, short8 b, f32x4 c) {
  return __builtin_amdgcn_mfma_f32_16x16x32_bf16(
      __builtin_bit_cast(bf16x8, a), __builtin_bit_cast(bf16x8, b), c, 0, 0, 0);
}

// Stage 16 elements (f32->bf16 convert, or bf16 passthrough) into LDS row.
template <typename S>
__device__ __forceinline__ void stage16(const S* __restrict__ g, short* __restrict__ dst) {
  short8 t0, t1;
  if constexpr (sizeof(S) == 4) {
    const f32x4* p = (const f32x4*)g;
    f32x4 v0 = p[0], v1 = p[1], v2 = p[2], v3 = p[3];
#pragma unroll
    for (int q = 0; q < 4; ++q) {
      t0[q]     = f2bf(v0[q]); t0[4 + q] = f2bf(v1[q]);
      t1[q]     = f2bf(v2[q]); t1[4 + q] = f2bf(v3[q]);
    }
  } else {
    const short8* p = (const short8*)g;
    t0 = p[0]; t1 = p[1];
  }
  *(short8*)dst       = t0;
  *(short8*)(dst + 8) = t1;
}

// ---------------------------------------------------------------------------
// GEMM: C[M][N] = A[M][K] * B[N][K]^T. 128x128 tile, BK=32, 4 waves.
// SA/SB in {float, short(bf16)}, SC in {float, short(bf16)}.
// M,N multiples of 128; K multiple of 32.
// ---------------------------------------------------------------------------
template <typename SA, typename SB, typename SC>
__global__ __launch_bounds__(256) void gemm_bt(const SA* __restrict__ A,
                                               const SB* __restrict__ B,
                                               SC* __restrict__ C,
                                               int M, int N, int K) {
  __shared__ short a_lds[128][40];   // +8 pad: 16B-aligned rows, bank-spread
  __shared__ short b_lds[128][40];

  const int tid  = threadIdx.x;
  const int lane = tid & 63;
  const int w    = tid >> 6;
  const int wr   = w >> 1, wc = w & 1;
  const int g    = lane >> 4;   // 0..3
  const int r    = lane & 15;   // 0..15
  const int nb   = N >> 7;
  const int brow = (blockIdx.x / nb) << 7;
  const int bcol = (blockIdx.x % nb) << 7;

  f32x4 acc[4][4];
#pragma unroll
  for (int i = 0; i < 4; ++i)
#pragma unroll
    for (int j = 0; j < 4; ++j) acc[i][j] = (f32x4){0.f, 0.f, 0.f, 0.f};

  const int srow  = tid >> 1;   // 0..127
  const int shalf = tid & 1;    // 0..1

  for (int k0 = 0; k0 < K; k0 += 32) {
    __syncthreads();
    stage16(A + (size_t)(brow + srow) * K + k0 + shalf * 16, &a_lds[srow][shalf * 16]);
    stage16(B + (size_t)(bcol + srow) * K + k0 + shalf * 16, &b_lds[srow][shalf * 16]);
    __syncthreads();

    short8 af[4], bfr[4];
#pragma unroll
    for (int i = 0; i < 4; ++i) af[i]  = *(const short8*)&a_lds[wr * 64 + i * 16 + r][g * 8];
#pragma unroll
    for (int j = 0; j < 4; ++j) bfr[j] = *(const short8*)&b_lds[wc * 64 + j * 16 + r][g * 8];
#pragma unroll
    for (int i = 0; i < 4; ++i)
#pragma unroll
      for (int j = 0; j < 4; ++j)
        acc[i][j] = mfma16(af[i], bfr[j], acc[i][j]);
  }

#pragma unroll
  for (int i = 0; i < 4; ++i) {
    const int row0 = brow + wr * 64 + i * 16 + g * 4;
#pragma unroll
    for (int j = 0; j < 4; ++j) {
      const int col = bcol + wc * 64 + j * 16 + r;
#pragma unroll
      for (int rr = 0; rr < 4; ++rr) {
        float v = acc[i][j][rr];
        if constexpr (sizeof(SC) == 2) C[(size_t)(row0 + rr) * N + col] = f2bf(v);
        else                           C[(size_t)(row0 + rr) * N + col] = v;
      }
    }
  }
}

// ---------------------------------------------------------------------------
// kv[m][kd][dv] = sum_s T_m(clamp(k[s][kd]*0.125)) * v[s][dv], per (b,h,m).
// Block = one (b,h,m), 4 waves; wave w owns kd rows [w*16, w*16+16).
// Exits immediately if beta[h][m] == 0 (kv slot never read in that case).
// ---------------------------------------------------------------------------
__global__ __launch_bounds__(256) void kv_kernel(const short* __restrict__ qkv,
                                                 const float* __restrict__ beta,
                                                 float* __restrict__ kv) {
  const int blk = blockIdx.x;
  const int m   = blk % MD;
  const int bh  = blk / MD;
  const int b   = bh >> 4, h = bh & 15;
  if (beta[h * MD + m] == 0.f) return;

  __shared__ float kT[64][84];    // clamped, scaled k^T  [kd][s]; stride 84 dw (==20 mod 32)
  __shared__ short vT[64][104];   // bf16 v^T [dv][s]; stride 52 dw (==20 mod 32)

  const int tid  = threadIdx.x;
  const int lane = tid & 63;
  const int w    = tid >> 6;
  const int g    = lane >> 4;
  const int r    = lane & 15;

  f32x4 acc[4];
#pragma unroll
  for (int j = 0; j < 4; ++j) acc[j] = (f32x4){0.f, 0.f, 0.f, 0.f};

  const int srl  = tid >> 2;   // 0..63 (staging row)
  const int part = tid & 3;    // 0..3  (16-col chunk)

  const size_t base = (size_t)b * SEQ * (3 * DMODEL);
  const int kcol = DMODEL     + h * 64 + part * 16;
  const int vcol = 2 * DMODEL + h * 64 + part * 16;

  for (int sc = 0; sc < SEQ; sc += 64) {
    __syncthreads();
    {
      const short* gk = qkv + base + (size_t)(sc + srl) * (3 * DMODEL) + kcol;
      const short* gv = qkv + base + (size_t)(sc + srl) * (3 * DMODEL) + vcol;
      short8 h0 = *(const short8*)gk;
      short8 h1 = *(const short8*)(gk + 8);
      short8 v0 = *(const short8*)gv;
      short8 v1 = *(const short8*)(gv + 8);
#pragma unroll
      for (int q = 0; q < 8; ++q) {
        kT[part * 16 + q][srl]     = fminf(fmaxf(bf2f(h0[q]) * 0.125f, -1.f), 1.f);
        kT[part * 16 + 8 + q][srl] = fminf(fmaxf(bf2f(h1[q]) * 0.125f, -1.f), 1.f);
        vT[part * 16 + q][srl]     = v0[q];
        vT[part * 16 + 8 + q][srl] = v1[q];
      }
    }
    __syncthreads();

#pragma unroll
    for (int kt = 0; kt < 2; ++kt) {
      const int s0 = kt * 32 + g * 8;
      float x[8];
      *(f32x4*)&x[0] = *(const f32x4*)&kT[w * 16 + r][s0];
      *(f32x4*)&x[4] = *(const f32x4*)&kT[w * 16 + r][s0 + 4];
      short8 af;
      if (m == 0) {
#pragma unroll
        for (int q = 0; q < 8; ++q) af[q] = (short)0x3F80;   // 1.0 bf16
      } else {
        float Tp[8], Tc[8];
#pragma unroll
        for (int q = 0; q < 8; ++q) { Tp[q] = 1.f; Tc[q] = x[q]; }
        for (int mm = 1; mm < m; ++mm) {
#pragma unroll
          for (int q = 0; q < 8; ++q) {
            float Tn = 2.f * x[q] * Tc[q] - Tp[q];
            Tp[q] = Tc[q]; Tc[q] = Tn;
          }
        }
#pragma unroll
        for (int q = 0; q < 8; ++q) af[q] = f2bf(Tc[q]);
      }
#pragma unroll
      for (int j = 0; j < 4; ++j) {
        short8 bfg = *(const short8*)&vT[j * 16 + r][kt * 32 + g * 8];
        acc[j] = mfma16(af, bfg, acc[j]);
      }
    }
  }

  float* out = kv + (size_t)(bh * MD + m) * (64 * 64);
#pragma unroll
  for (int j = 0; j < 4; ++j) {
    const int kd = w * 16 + g * 4;
    const int dv = j * 16 + r;
#pragma unroll
    for (int rr = 0; rr < 4; ++rr) out[(size_t)(kd + rr) * 64 + dv] = acc[j][rr];
  }
}

// ---------------------------------------------------------------------------
// attn[s][h*64+dv] = sum_{active m} beta_m * sum_kd T_m(q~[s][kd]) kv[m][kd][dv]
// Block = (b,h, 256 s-rows); 4 waves x 4 s-tiles of 16. kv staged bf16,
// transposed [dv][am*64+kd] in LDS. Cheb recurrence per lane in f32.
// ---------------------------------------------------------------------------
__global__ __launch_bounds__(256) void attn_kernel(const short* __restrict__ qkv,
                                                   const float* __restrict__ beta,
                                                   const float* __restrict__ kv,
                                                   short* __restrict__ attn) {
  const int bid  = blockIdx.x;
  const int bh   = bid >> 4;   // 0..31
  const int sblk = bid & 15;
  const int b    = bh >> 4, h = bh & 15;

  __shared__ short kvT[64][744];  // stride 372 dw (==20 mod 32), rows 16B-aligned

  const int tid  = threadIdx.x;
  const int lane = tid & 63;
  const int w    = tid >> 6;
  const int g    = lane >> 4;
  const int r    = lane & 15;

  float betav[MD];
#pragma unroll
  for (int mm = 0; mm < MD; ++mm) betav[mm] = beta[h * MD + mm];

  // stage active kv slices (f32 -> bf16, transposed)
  {
    int am = 0;
#pragma unroll
    for (int mm = 0; mm < MD; ++mm) {
      if (betav[mm] != 0.f) {
        const float* src = kv + (size_t)(bh * MD + mm) * 4096;
        for (int e = tid; e < 4096; e += 256) {
          const int kd = e >> 6, dv = e & 63;
          kvT[dv][am * 64 + kd] = f2bf(src[e]);
        }
        ++am;
      }
    }
  }
  __syncthreads();

  const size_t qbase = (size_t)b * SEQ * (3 * DMODEL) + (size_t)h * 64;

#pragma unroll 1
  for (int st = 0; st < 4; ++st) {
    const int srow = sblk * 256 + w * 64 + st * 16 + r;
    const short* gq = qkv + qbase + (size_t)srow * (3 * DMODEL);
    short8 q0 = *(const short8*)(gq + g * 8);
    short8 q1 = *(const short8*)(gq + 32 + g * 8);
    float x[16];
#pragma unroll
    for (int q = 0; q < 8; ++q) {
      x[q]     = fminf(fmaxf(bf2f(q0[q]) * 0.125f, -1.f), 1.f);
      x[8 + q] = fminf(fmaxf(bf2f(q1[q]) * 0.125f, -1.f), 1.f);
    }
    float Tp[16], Tc[16];
#pragma unroll
    for (int q = 0; q < 16; ++q) { Tp[q] = 1.f; Tc[q] = x[q]; }
    f32x4 acc[4];
#pragma unroll
    for (int j = 0; j < 4; ++j) acc[j] = (f32x4){0.f, 0.f, 0.f, 0.f};

    int am = 0;
#pragma unroll
    for (int mt = 0; mt < MD; ++mt) {
      if (mt >= 2) {   // advance recurrence so Tc == T_mt
#pragma unroll
        for (int q = 0; q < 16; ++q) {
          float Tn = 2.f * x[q] * Tc[q] - Tp[q];
          Tp[q] = Tc[q]; Tc[q] = Tn;
        }
      }
      if (betav[mt] != 0.f) {
        const float bm = betav[mt];
        short8 a0, a1;
        if (mt == 0) {
          const short one = f2bf(bm);
#pragma unroll
          for (int q = 0; q < 8; ++q) { a0[q] = one; a1[q] = one; }
        } else {
#pragma unroll
          for (int q = 0; q < 8; ++q) {
            a0[q] = f2bf(bm * Tc[q]);
            a1[q] = f2bf(bm * Tc[8 + q]);
          }
        }
#pragma unroll
        for (int j = 0; j < 4; ++j) {
          short8 b0 = *(const short8*)&kvT[j * 16 + r][am * 64 + g * 8];
          acc[j] = mfma16(a0, b0, acc[j]);
          short8 b1 = *(const short8*)&kvT[j * 16 + r][am * 64 + 32 + g * 8];
          acc[j] = mfma16(a1, b1, acc[j]);
        }
        ++am;
      }
    }

#pragma unroll
    for (int j = 0; j < 4; ++j) {
      const int col = h * 64 + j * 16 + r;
#pragma unroll
      for (int rr = 0; rr < 4; ++rr) {
        const int sr = sblk * 256 + w * 64 + st * 16 + g * 4 + rr;
        attn[(size_t)(b * SEQ + sr) * DMODEL + col] = f2bf(acc[j][rr]);
      }
    }
  }
}

// ---------------------------------------------------------------------------
extern "C" void kernel_launch(void* const* d_in, const int* in_sizes, int n_in,
                              void* d_out, int out_size, void* d_ws, size_t ws_size,
                              hipStream_t stream) {
  const float* x     = (const float*)d_in[0];
  const float* w_in  = (const float*)d_in[1];
  const float* w_out = (const float*)d_in[2];
  const float* beta  = (const float*)d_in[3];
  float* out = (float*)d_out;

  char* ws = (char*)d_ws;
  short* qkv   = (short*)ws;                                  // 8192*3072*2  = 50331648 B
  float* kvbuf = (float*)(ws + 50331648);                     // 32*11*64*64*4 = 5767168 B
  short* attn  = (short*)(ws + 50331648 + 5767168);           // 8192*1024*2  = 16777216 B

  const int Mrows = BATCH * SEQ;  // 8192

  // 1) qkv = x @ w_in^T        (8192 x 3072 x 1024)
  gemm_bt<float, float, short><<<dim3((Mrows / 128) * (3 * DMODEL / 128)), dim3(256), 0, stream>>>(
      x, w_in, qkv, Mrows, 3 * DMODEL, DMODEL);

  // 2) kv state per (b,h,m)
  kv_kernel<<<dim3(BATCH * NH * MD), dim3(256), 0, stream>>>(qkv, beta, kvbuf);

  // 3) attn = sum_m beta_m T_m(q) @ kv_m
  attn_kernel<<<dim3(32 * 16), dim3(256), 0, stream>>>(qkv, beta, kvbuf, attn);

  // 4) out = attn @ w_out^T    (8192 x 1024 x 1024)
  gemm_bt<short, float, float><<<dim3((Mrows / 128) * (DMODEL / 128)), dim3(256), 0, stream>>>(
      attn, w_out, out, Mrows, DMODEL, DMODEL);
}

// Round 5
// 195.728 us; speedup vs baseline: 1.6236x; 1.6236x over previous
//
#include <hip/hip_runtime.h>
#include <hip/hip_bf16.h>

// ---------------------------------------------------------------------------
// CollapsedPBFA: x->(qkv GEMM)->cheb-kernelized linear attention->out GEMM
// R4b: same as R4, with the short4 name collision fixed (HIP predefines
// short4; renamed to s16x4).
// ---------------------------------------------------------------------------

#define SEQ    4096
#define BATCH  2
#define DMODEL 1024
#define NH     16
#define DH     64
#define MD     11
#define NCH    8
#define CHUNK  512   // SEQ / NCH

typedef __attribute__((ext_vector_type(8)))  short  short8;
typedef __attribute__((ext_vector_type(4)))  short  s16x4;
typedef __attribute__((ext_vector_type(8)))  __bf16 bf16x8;
typedef __attribute__((ext_vector_type(4)))  float  f32x4;

__device__ __forceinline__ short f2bf(float f) {
  union { float f; unsigned u; } c; c.f = f;
  unsigned r = c.u + 0x7FFFu + ((c.u >> 16) & 1u);
  return (short)(r >> 16);
}
__device__ __forceinline__ float bf2f(short h) {
  union { unsigned u; float f; } c; c.u = ((unsigned)(unsigned short)h) << 16;
  return c.f;
}

__device__ __forceinline__ f32x4 mfma16(short8 a, short8 b, f32x4 c) {
  return __builtin_amdgcn_mfma_f32_16x16x32_bf16(
      __builtin_bit_cast(bf16x8, a), __builtin_bit_cast(bf16x8, b), c, 0, 0, 0);
}

typedef const __attribute__((address_space(1))) void* gvp;
typedef __attribute__((address_space(3))) void* lvp;
// Async global->LDS, 16B per lane. dst is wave-uniform base; lane i lands at
// dst + 16*i (m97 pattern).
__device__ __forceinline__ void gload16(const void* g, void* l) {
  __builtin_amdgcn_global_load_lds((gvp)g, (lvp)l, 16, 0, 0);
}

// ---------------------------------------------------------------------------
// f32 -> bf16 elementwise convert (vectorized).
// ---------------------------------------------------------------------------
__global__ __launch_bounds__(256) void to_bf16(const float* __restrict__ src,
                                               short* __restrict__ dst, int n4) {
  int i = blockIdx.x * 256 + threadIdx.x;
  if (i < n4) {
    f32x4 v = ((const f32x4*)src)[i];
    s16x4 o;
#pragma unroll
    for (int q = 0; q < 4; ++q) o[q] = f2bf(v[q]);
    ((s16x4*)dst)[i] = o;
  }
}

// ---------------------------------------------------------------------------
// GEMM: C[M][N] = A[M][K] * B[N][K]^T, A/B bf16. 128x128 tile, BK=32, 4 waves,
// global_load_lds width-16 staging into linear LDS (m97 structure).
// ---------------------------------------------------------------------------
template <typename SC>
__global__ __launch_bounds__(256) void gemm_bt(const short* __restrict__ A,
                                               const short* __restrict__ B,
                                               SC* __restrict__ C,
                                               int M, int N, int K) {
  __shared__ short aT[128][32];   // linear, no pad (gload_lds requirement)
  __shared__ short bT[128][32];

  const int tid  = threadIdx.x;
  const int lane = tid & 63;
  const int w    = tid >> 6;
  const int wr   = w >> 1, wc = w & 1;
  const int g    = lane >> 4;   // 0..3
  const int r    = lane & 15;   // 0..15
  const int nb   = N >> 7;
  const int brow = (blockIdx.x / nb) << 7;
  const int bcol = (blockIdx.x % nb) << 7;

  f32x4 acc[4][4];
#pragma unroll
  for (int i = 0; i < 4; ++i)
#pragma unroll
    for (int j = 0; j < 4; ++j) acc[i][j] = (f32x4){0.f, 0.f, 0.f, 0.f};

  for (int k0 = 0; k0 < K; k0 += 32) {
    __syncthreads();
    {
      const short* ga0 = A + (size_t)(brow + w * 32 + (lane >> 2)) * K + k0 + (lane & 3) * 8;
      const short* gb0 = B + (size_t)(bcol + w * 32 + (lane >> 2)) * K + k0 + (lane & 3) * 8;
      gload16(ga0, &aT[w * 32][0]);
      gload16(ga0 + (size_t)16 * K, &aT[w * 32 + 16][0]);
      gload16(gb0, &bT[w * 32][0]);
      gload16(gb0 + (size_t)16 * K, &bT[w * 32 + 16][0]);
    }
    __syncthreads();

    short8 af[4], bfr[4];
#pragma unroll
    for (int i = 0; i < 4; ++i) af[i]  = *(const short8*)&aT[wr * 64 + i * 16 + r][g * 8];
#pragma unroll
    for (int j = 0; j < 4; ++j) bfr[j] = *(const short8*)&bT[wc * 64 + j * 16 + r][g * 8];
#pragma unroll
    for (int i = 0; i < 4; ++i)
#pragma unroll
      for (int j = 0; j < 4; ++j)
        acc[i][j] = mfma16(af[i], bfr[j], acc[i][j]);
  }

#pragma unroll
  for (int i = 0; i < 4; ++i) {
    const int row0 = brow + wr * 64 + i * 16 + g * 4;
#pragma unroll
    for (int j = 0; j < 4; ++j) {
      const int col = bcol + wc * 64 + j * 16 + r;
#pragma unroll
      for (int rr = 0; rr < 4; ++rr) {
        float v = acc[i][j][rr];
        if constexpr (sizeof(SC) == 2) C[(size_t)(row0 + rr) * N + col] = f2bf(v);
        else                           C[(size_t)(row0 + rr) * N + col] = v;
      }
    }
  }
}

// ---------------------------------------------------------------------------
// kv partial: block = (bh, chunk of 512 s-rows). Stage k~ (clamped, scaled,
// bf16-exact) and v transposed into chunk-resident LDS ONCE, then loop all
// active m over the resident tile. acc[4] only (compile-time indexed);
// Chebyshev recurrence restarted per (m, kt) from LDS x.
// partial[bh][m][chunk][kd*64+dv] in bf16.
// ---------------------------------------------------------------------------
__global__ __launch_bounds__(256) void kv_partial(const short* __restrict__ qkv,
                                                  const float* __restrict__ beta,
                                                  short* __restrict__ partial) {
  const int bh = blockIdx.x / NCH;
  const int ch = blockIdx.x % NCH;
  const int b  = bh >> 4, h = bh & 15;

  __shared__ short kT[64][522];   // [kd][s], stride 261 dw (odd -> spread banks)
  __shared__ short vT[64][522];   // [dv][s]

  const int tid  = threadIdx.x;
  const int lane = tid & 63;
  const int w    = tid >> 6;
  const int g    = lane >> 4;
  const int r    = lane & 15;

  // ---- stage the whole 512-row chunk (transposed), one barrier total ----
  const int srl  = tid >> 2;   // 0..63
  const int part = tid & 3;    // 0..3
  const size_t base = (size_t)b * SEQ * 3072 + (size_t)(ch * CHUNK) * 3072;
  const int kcol = DMODEL     + h * 64 + part * 16;
  const int vcol = 2 * DMODEL + h * 64 + part * 16;

#pragma unroll
  for (int ss = 0; ss < CHUNK; ss += 64) {
    const short* gk = qkv + base + (size_t)(ss + srl) * 3072 + kcol;
    const short* gv = qkv + base + (size_t)(ss + srl) * 3072 + vcol;
    short8 k0 = *(const short8*)gk;
    short8 k1 = *(const short8*)(gk + 8);
    short8 v0 = *(const short8*)gv;
    short8 v1 = *(const short8*)(gv + 8);
    const int sidx = ss + srl;
#pragma unroll
    for (int q = 0; q < 8; ++q) {
      // clamp(k*0.125) is exactly representable in bf16 (exponent shift only)
      kT[part * 16 + q][sidx]     = f2bf(fminf(fmaxf(bf2f(k0[q]) * 0.125f, -1.f), 1.f));
      kT[part * 16 + 8 + q][sidx] = f2bf(fminf(fmaxf(bf2f(k1[q]) * 0.125f, -1.f), 1.f));
      vT[part * 16 + q][sidx]     = v0[q];
      vT[part * 16 + 8 + q][sidx] = v1[q];
    }
  }
  __syncthreads();

  // ---- per active m: full pass over resident chunk ----
  for (int m = 0; m < MD; ++m) {
    if (beta[h * MD + m] == 0.f) continue;

    f32x4 acc[4];
#pragma unroll
    for (int j = 0; j < 4; ++j) acc[j] = (f32x4){0.f, 0.f, 0.f, 0.f};

#pragma unroll 1
    for (int kt = 0; kt < CHUNK / 32; ++kt) {
      const int s0 = kt * 32 + g * 8;
      short8 af;
      if (m == 0) {
#pragma unroll
        for (int q = 0; q < 8; ++q) af[q] = (short)0x3F80;
      } else {
        short8 xs = *(const short8*)&kT[w * 16 + r][s0];
        float Tp[8], Tc[8];
#pragma unroll
        for (int q = 0; q < 8; ++q) { float xv = bf2f(xs[q]); Tp[q] = 1.f; Tc[q] = xv; }
        for (int mm = 1; mm < m; ++mm) {
#pragma unroll
          for (int q = 0; q < 8; ++q) {
            float xv = bf2f(xs[q]);
            float Tn = 2.f * xv * Tc[q] - Tp[q];
            Tp[q] = Tc[q]; Tc[q] = Tn;
          }
        }
#pragma unroll
        for (int q = 0; q < 8; ++q) af[q] = f2bf(Tc[q]);
      }
#pragma unroll
      for (int j = 0; j < 4; ++j) {
        short8 bfg = *(const short8*)&vT[j * 16 + r][s0];
        acc[j] = mfma16(af, bfg, acc[j]);
      }
    }

    short* po = partial + ((size_t)(bh * MD + m) * NCH + ch) * 4096;
#pragma unroll
    for (int j = 0; j < 4; ++j) {
      const int kd = w * 16 + g * 4;
      const int dv = j * 16 + r;
#pragma unroll
      for (int rr = 0; rr < 4; ++rr) po[(size_t)(kd + rr) * 64 + dv] = f2bf(acc[j][rr]);
    }
  }
}

// ---------------------------------------------------------------------------
// reduce partials -> kvbuf f32. Block per (bh, m); inactive m exit.
// ---------------------------------------------------------------------------
__global__ __launch_bounds__(256) void kv_reduce(const short* __restrict__ partial,
                                                 const float* __restrict__ beta,
                                                 float* __restrict__ kv) {
  const int m  = blockIdx.x % MD;
  const int bh = blockIdx.x / MD;
  const int h  = bh & 15;
  if (beta[h * MD + m] == 0.f) return;

  const int tid = threadIdx.x;
  const short* src = partial + (size_t)(bh * MD + m) * NCH * 4096;
  float* dst = kv + (size_t)(bh * MD + m) * 4096;
#pragma unroll
  for (int e0 = 0; e0 < 4096; e0 += 256) {
    float s = 0.f;
#pragma unroll
    for (int c = 0; c < NCH; ++c) s += bf2f(src[c * 4096 + e0 + tid]);
    dst[e0 + tid] = s;
  }
}

// ---------------------------------------------------------------------------
// attn: unchanged from R3 (passed; not the top bottleneck).
// ---------------------------------------------------------------------------
__global__ __launch_bounds__(256) void attn_kernel(const short* __restrict__ qkv,
                                                   const float* __restrict__ beta,
                                                   const float* __restrict__ kv,
                                                   short* __restrict__ attn) {
  const int bid  = blockIdx.x;
  const int bh   = bid >> 4;
  const int sblk = bid & 15;
  const int b    = bh >> 4, h = bh & 15;

  __shared__ short kvT[64][744];

  const int tid  = threadIdx.x;
  const int lane = tid & 63;
  const int w    = tid >> 6;
  const int g    = lane >> 4;
  const int r    = lane & 15;

  float betav[MD];
#pragma unroll
  for (int mm = 0; mm < MD; ++mm) betav[mm] = beta[h * MD + mm];

  {
    int am = 0;
#pragma unroll
    for (int mm = 0; mm < MD; ++mm) {
      if (betav[mm] != 0.f) {
        const float* src = kv + (size_t)(bh * MD + mm) * 4096;
        for (int e = tid; e < 4096; e += 256) {
          const int kd = e >> 6, dv = e & 63;
          kvT[dv][am * 64 + kd] = f2bf(src[e]);
        }
        ++am;
      }
    }
  }
  __syncthreads();

  const size_t qbase = (size_t)b * SEQ * 3072 + (size_t)h * 64;

#pragma unroll 1
  for (int st = 0; st < 4; ++st) {
    const int srow = sblk * 256 + w * 64 + st * 16 + r;
    const short* gq = qkv + qbase + (size_t)srow * 3072;
    short8 q0 = *(const short8*)(gq + g * 8);
    short8 q1 = *(const short8*)(gq + 32 + g * 8);
    float x[16];
#pragma unroll
    for (int q = 0; q < 8; ++q) {
      x[q]     = fminf(fmaxf(bf2f(q0[q]) * 0.125f, -1.f), 1.f);
      x[8 + q] = fminf(fmaxf(bf2f(q1[q]) * 0.125f, -1.f), 1.f);
    }
    float Tp[16], Tc[16];
#pragma unroll
    for (int q = 0; q < 16; ++q) { Tp[q] = 1.f; Tc[q] = x[q]; }
    f32x4 acc[4];
#pragma unroll
    for (int j = 0; j < 4; ++j) acc[j] = (f32x4){0.f, 0.f, 0.f, 0.f};

    int am = 0;
#pragma unroll
    for (int mt = 0; mt < MD; ++mt) {
      if (mt >= 2) {
#pragma unroll
        for (int q = 0; q < 16; ++q) {
          float Tn = 2.f * x[q] * Tc[q] - Tp[q];
          Tp[q] = Tc[q]; Tc[q] = Tn;
        }
      }
      if (betav[mt] != 0.f) {
        const float bm = betav[mt];
        short8 a0, a1;
        if (mt == 0) {
          const short one = f2bf(bm);
#pragma unroll
          for (int q = 0; q < 8; ++q) { a0[q] = one; a1[q] = one; }
        } else {
#pragma unroll
          for (int q = 0; q < 8; ++q) {
            a0[q] = f2bf(bm * Tc[q]);
            a1[q] = f2bf(bm * Tc[8 + q]);
          }
        }
#pragma unroll
        for (int j = 0; j < 4; ++j) {
          short8 b0 = *(const short8*)&kvT[j * 16 + r][am * 64 + g * 8];
          acc[j] = mfma16(a0, b0, acc[j]);
          short8 b1 = *(const short8*)&kvT[j * 16 + r][am * 64 + 32 + g * 8];
          acc[j] = mfma16(a1, b1, acc[j]);
        }
        ++am;
      }
    }

#pragma unroll
    for (int j = 0; j < 4; ++j) {
      const int col = h * 64 + j * 16 + r;
#pragma unroll
      for (int rr = 0; rr < 4; ++rr) {
        const int sr = sblk * 256 + w * 64 + st * 16 + g * 4 + rr;
        attn[(size_t)(b * SEQ + sr) * DMODEL + col] = f2bf(acc[j][rr]);
      }
    }
  }
}

// ---------------------------------------------------------------------------
extern "C" void kernel_launch(void* const* d_in, const int* in_sizes, int n_in,
                              void* d_out, int out_size, void* d_ws, size_t ws_size,
                              hipStream_t stream) {
  const float* x     = (const float*)d_in[0];
  const float* w_in  = (const float*)d_in[1];
  const float* w_out = (const float*)d_in[2];
  const float* beta  = (const float*)d_in[3];
  float* out = (float*)d_out;

  char* ws = (char*)d_ws;
  // ws layout (region-unioned; total 87,556,096 B):
  //   qkv    short  50,331,648
  //   kvbuf  float   5,767,168
  //   w_inb  short   6,291,456
  //   w_outb short   2,097,152
  //   regionU: xb(16.8MB, preconv->gemm1) / partial(23.1MB, kv_partial->reduce)
  //            / attn(16.8MB, attn->gemm2) -- lifetimes strictly ordered.
  short* qkv     = (short*)ws;
  float* kvbuf   = (float*)(ws + 50331648);
  short* w_inb   = (short*)(ws + 56098816);
  short* w_outb  = (short*)(ws + 62390272);
  char*  regionU = ws + 64487424;
  short* xb      = (short*)regionU;
  short* partial = (short*)regionU;
  short* attn    = (short*)regionU;

  const int Mrows = BATCH * SEQ;  // 8192

  // 0) pre-convert f32 -> bf16
  to_bf16<<<dim3(8192), dim3(256), 0, stream>>>(x,     xb,     2097152);
  to_bf16<<<dim3(3072), dim3(256), 0, stream>>>(w_in,  w_inb,   786432);
  to_bf16<<<dim3(1024), dim3(256), 0, stream>>>(w_out, w_outb,  262144);

  // 1) qkv = x @ w_in^T        (8192 x 3072 x 1024)
  gemm_bt<short><<<dim3((Mrows / 128) * (3 * DMODEL / 128)), dim3(256), 0, stream>>>(
      xb, w_inb, qkv, Mrows, 3 * DMODEL, DMODEL);

  // 2) kv partials over s-chunks, then reduce
  kv_partial<<<dim3(BATCH * NH * NCH), dim3(256), 0, stream>>>(qkv, beta, partial);
  kv_reduce<<<dim3(BATCH * NH * MD), dim3(256), 0, stream>>>(partial, beta, kvbuf);

  // 3) attn = sum_m beta_m T_m(q) @ kv_m
  attn_kernel<<<dim3(32 * 16), dim3(256), 0, stream>>>(qkv, beta, kvbuf, attn);

  // 4) out = attn @ w_out^T    (8192 x 1024 x 1024)
  gemm_bt<float><<<dim3((Mrows / 128) * (DMODEL / 128)), dim3(256), 0, stream>>>(
      attn, w_outb, out, Mrows, DMODEL, DMODEL);
}

// Round 6
// 181.860 us; speedup vs baseline: 1.7474x; 1.0763x over previous
//
#include <hip/hip_runtime.h>
#include <hip/hip_bf16.h>

// ---------------------------------------------------------------------------
// CollapsedPBFA: x->(qkv GEMM)->cheb-kernelized linear attention->out GEMM
// R6: GEMMs rewritten as 256x128-tile BK=64 8-wave kernel with counted-vmcnt
//     double-buffer pipeline (T3+T4), XOR bank swizzle (T2, both-sides),
//     setprio around MFMA (T5), bijective XCD swizzle (T1).
//     kv_partial / kv_reduce / attn unchanged from R5 (passed, absmax 32).
// ---------------------------------------------------------------------------

#define SEQ    4096
#define BATCH  2
#define DMODEL 1024
#define NH     16
#define DH     64
#define MD     11
#define NCH    8
#define CHUNK  512   // SEQ / NCH

typedef __attribute__((ext_vector_type(8)))  short  short8;
typedef __attribute__((ext_vector_type(4)))  short  s16x4;
typedef __attribute__((ext_vector_type(8)))  __bf16 bf16x8;
typedef __attribute__((ext_vector_type(4)))  float  f32x4;

__device__ __forceinline__ short f2bf(float f) {
  union { float f; unsigned u; } c; c.f = f;
  unsigned r = c.u + 0x7FFFu + ((c.u >> 16) & 1u);
  return (short)(r >> 16);
}
__device__ __forceinline__ float bf2f(short h) {
  union { unsigned u; float f; } c; c.u = ((unsigned)(unsigned short)h) << 16;
  return c.f;
}

__device__ __forceinline__ f32x4 mfma16(short8 a, short8 b, f32x4 c) {
  return __builtin_amdgcn_mfma_f32_16x16x32_bf16(
      __builtin_bit_cast(bf16x8, a), __builtin_bit_cast(bf16x8, b), c, 0, 0, 0);
}

typedef const __attribute__((address_space(1))) void* gvp;
typedef __attribute__((address_space(3))) void* lvp;
// Async global->LDS, 16B per lane: lane i lands at (uniform dst) + 16*i.
__device__ __forceinline__ void gload16(const void* g, void* l) {
  __builtin_amdgcn_global_load_lds((gvp)g, (lvp)l, 16, 0, 0);
}

// ---------------------------------------------------------------------------
// f32 -> bf16 elementwise convert (vectorized).
// ---------------------------------------------------------------------------
__global__ __launch_bounds__(256) void to_bf16(const float* __restrict__ src,
                                               short* __restrict__ dst, int n4) {
  int i = blockIdx.x * 256 + threadIdx.x;
  if (i < n4) {
    f32x4 v = ((const f32x4*)src)[i];
    s16x4 o;
#pragma unroll
    for (int q = 0; q < 4; ++q) o[q] = f2bf(v[q]);
    ((s16x4*)dst)[i] = o;
  }
}

// ---------------------------------------------------------------------------
// GEMM: C[M][N] = A[M][K] * B[N][K]^T, A/B bf16.
// Tile 256x128, BK=64, 512 threads = 8 waves (WM=4 x WN=2), per-wave 64x64.
// Double-buffered LDS (96KB), counted vmcnt(6) pipeline, XOR chunk swizzle.
// Requires: M%256==0, N%128==0, K%64==0, K>=128, grid%8==0.
// ---------------------------------------------------------------------------
template <typename SC>
__global__ __launch_bounds__(512) void gemm256(const short* __restrict__ A,
                                               const short* __restrict__ B,
                                               SC* __restrict__ C,
                                               int M, int N, int K) {
  // LDS (shorts): A bufs @0,@16384 (256x64 each), B bufs @32768,@40960 (128x64)
  __shared__ short lds[49152];

  const int tid  = threadIdx.x;
  const int lane = tid & 63;
  const int w    = tid >> 6;        // 0..7
  const int wm   = w >> 1;          // 0..3
  const int wn   = w & 1;           // 0..1
  const int g    = lane >> 4;       // 0..3
  const int r    = lane & 15;       // 0..15

  const int nbn = N >> 7;
  int bid = blockIdx.x;
  {  // bijective XCD swizzle (gridDim.x % 8 == 0 for all our shapes)
    const int cpx = gridDim.x >> 3;
    bid = (bid & 7) * cpx + (bid >> 3);
  }
  const int brow = (bid / nbn) << 8;
  const int bcol = (bid % nbn) << 7;
  const int NT   = K >> 6;

  // staging lane geometry: per gload16 issue a wave covers 8 rows x 64 cols.
  const int lr    = lane >> 3;                    // row within wave's 8-row strip
  const int lc    = lane & 7;                     // 16B chunk within row
  const int swz_w = ((w * 8 + lr) >> 1) & 7;      // row-derived chunk swizzle
  const int cgs   = (lc ^ swz_w) * 8;             // pre-swizzled global col (shorts)

  // read-side swizzle (row = ...*16 + r; 16s contribute 0 mod 8 after >>1)
  const int swz_r = (r >> 1) & 7;

  f32x4 acc[4][4];
#pragma unroll
  for (int mi = 0; mi < 4; ++mi)
#pragma unroll
    for (int ni = 0; ni < 4; ++ni) acc[mi][ni] = (f32x4){0.f, 0.f, 0.f, 0.f};

  // ---- staging: 4 A-issues (64 rows each) + 2 B-issues per K-tile ----
  auto STAGE = [&](int buf, int t) {
    const int k0 = t << 6;
    short* ab = &lds[buf * 16384];
    short* bb = &lds[32768 + buf * 8192];
#pragma unroll
    for (int i = 0; i < 4; ++i) {
      const short* ga = A + (size_t)(brow + i * 64 + w * 8 + lr) * K + k0 + cgs;
      gload16(ga, ab + (i * 64 + w * 8) * 64);
    }
#pragma unroll
    for (int i = 0; i < 2; ++i) {
      const short* gb = B + (size_t)(bcol + i * 64 + w * 8 + lr) * K + k0 + cgs;
      gload16(gb, bb + (i * 64 + w * 8) * 64);
    }
  };

  // ---- prologue: 2 K-tiles in flight ----
  STAGE(0, 0);
  STAGE(1, 1);
  asm volatile("s_waitcnt vmcnt(6)" ::: "memory");   // tile 0 landed
  __builtin_amdgcn_sched_barrier(0);
  __builtin_amdgcn_s_barrier();

  for (int kt = 0; kt < NT; ++kt) {
    const int cur = kt & 1;
    const short* ab = &lds[cur * 16384];
    const short* bb = &lds[32768 + cur * 8192];

    short8 av[4][2], bv[4][2];
#pragma unroll
    for (int mi = 0; mi < 4; ++mi)
#pragma unroll
      for (int ks = 0; ks < 2; ++ks)
        av[mi][ks] = *(const short8*)(ab + (wm * 64 + mi * 16 + r) * 64 +
                                      (((ks * 4 + g) ^ swz_r) * 8));
#pragma unroll
    for (int ni = 0; ni < 4; ++ni)
#pragma unroll
      for (int ks = 0; ks < 2; ++ks)
        bv[ni][ks] = *(const short8*)(bb + (wn * 64 + ni * 16 + r) * 64 +
                                      (((ks * 4 + g) ^ swz_r) * 8));

    asm volatile("s_waitcnt lgkmcnt(0)" ::: "memory");  // frags in regs
    __builtin_amdgcn_sched_barrier(0);
    __builtin_amdgcn_s_barrier();                       // all waves done w/ cur

    if (kt + 2 < NT) STAGE(cur, kt + 2);                // overwrite cur buffer

    __builtin_amdgcn_s_setprio(1);
#pragma unroll
    for (int mi = 0; mi < 4; ++mi)
#pragma unroll
      for (int ni = 0; ni < 4; ++ni) {
        acc[mi][ni] = mfma16(av[mi][0], bv[ni][0], acc[mi][ni]);
        acc[mi][ni] = mfma16(av[mi][1], bv[ni][1], acc[mi][ni]);
      }
    __builtin_amdgcn_s_setprio(0);

    if (kt + 2 < NT) { asm volatile("s_waitcnt vmcnt(6)" ::: "memory"); }
    else             { asm volatile("s_waitcnt vmcnt(0)" ::: "memory"); }
    __builtin_amdgcn_sched_barrier(0);
    __builtin_amdgcn_s_barrier();                       // next buffer ready
  }

#pragma unroll
  for (int mi = 0; mi < 4; ++mi) {
    const int row0 = brow + wm * 64 + mi * 16 + g * 4;
#pragma unroll
    for (int ni = 0; ni < 4; ++ni) {
      const int col = bcol + wn * 64 + ni * 16 + r;
#pragma unroll
      for (int rr = 0; rr < 4; ++rr) {
        float v = acc[mi][ni][rr];
        if constexpr (sizeof(SC) == 2) C[(size_t)(row0 + rr) * N + col] = f2bf(v);
        else                           C[(size_t)(row0 + rr) * N + col] = v;
      }
    }
  }
}

// ---------------------------------------------------------------------------
// kv partial: block = (bh, chunk of 512 s-rows). Stage k~/v transposed into
// chunk-resident LDS once, loop active m over the resident tile.
// ---------------------------------------------------------------------------
__global__ __launch_bounds__(256) void kv_partial(const short* __restrict__ qkv,
                                                  const float* __restrict__ beta,
                                                  short* __restrict__ partial) {
  const int bh = blockIdx.x / NCH;
  const int ch = blockIdx.x % NCH;
  const int b  = bh >> 4, h = bh & 15;

  __shared__ short kT[64][522];   // [kd][s], stride 261 dw
  __shared__ short vT[64][522];   // [dv][s]

  const int tid  = threadIdx.x;
  const int lane = tid & 63;
  const int w    = tid >> 6;
  const int g    = lane >> 4;
  const int r    = lane & 15;

  const int srl  = tid >> 2;
  const int part = tid & 3;
  const size_t base = (size_t)b * SEQ * 3072 + (size_t)(ch * CHUNK) * 3072;
  const int kcol = DMODEL     + h * 64 + part * 16;
  const int vcol = 2 * DMODEL + h * 64 + part * 16;

#pragma unroll
  for (int ss = 0; ss < CHUNK; ss += 64) {
    const short* gk = qkv + base + (size_t)(ss + srl) * 3072 + kcol;
    const short* gv = qkv + base + (size_t)(ss + srl) * 3072 + vcol;
    short8 k0 = *(const short8*)gk;
    short8 k1 = *(const short8*)(gk + 8);
    short8 v0 = *(const short8*)gv;
    short8 v1 = *(const short8*)(gv + 8);
    const int sidx = ss + srl;
#pragma unroll
    for (int q = 0; q < 8; ++q) {
      kT[part * 16 + q][sidx]     = f2bf(fminf(fmaxf(bf2f(k0[q]) * 0.125f, -1.f), 1.f));
      kT[part * 16 + 8 + q][sidx] = f2bf(fminf(fmaxf(bf2f(k1[q]) * 0.125f, -1.f), 1.f));
      vT[part * 16 + q][sidx]     = v0[q];
      vT[part * 16 + 8 + q][sidx] = v1[q];
    }
  }
  __syncthreads();

  for (int m = 0; m < MD; ++m) {
    if (beta[h * MD + m] == 0.f) continue;

    f32x4 acc[4];
#pragma unroll
    for (int j = 0; j < 4; ++j) acc[j] = (f32x4){0.f, 0.f, 0.f, 0.f};

#pragma unroll 1
    for (int kt = 0; kt < CHUNK / 32; ++kt) {
      const int s0 = kt * 32 + g * 8;
      short8 af;
      if (m == 0) {
#pragma unroll
        for (int q = 0; q < 8; ++q) af[q] = (short)0x3F80;
      } else {
        short8 xs = *(const short8*)&kT[w * 16 + r][s0];
        float Tp[8], Tc[8];
#pragma unroll
        for (int q = 0; q < 8; ++q) { float xv = bf2f(xs[q]); Tp[q] = 1.f; Tc[q] = xv; }
        for (int mm = 1; mm < m; ++mm) {
#pragma unroll
          for (int q = 0; q < 8; ++q) {
            float xv = bf2f(xs[q]);
            float Tn = 2.f * xv * Tc[q] - Tp[q];
            Tp[q] = Tc[q]; Tc[q] = Tn;
          }
        }
#pragma unroll
        for (int q = 0; q < 8; ++q) af[q] = f2bf(Tc[q]);
      }
#pragma unroll
      for (int j = 0; j < 4; ++j) {
        short8 bfg = *(const short8*)&vT[j * 16 + r][s0];
        acc[j] = mfma16(af, bfg, acc[j]);
      }
    }

    short* po = partial + ((size_t)(bh * MD + m) * NCH + ch) * 4096;
#pragma unroll
    for (int j = 0; j < 4; ++j) {
      const int kd = w * 16 + g * 4;
      const int dv = j * 16 + r;
#pragma unroll
      for (int rr = 0; rr < 4; ++rr) po[(size_t)(kd + rr) * 64 + dv] = f2bf(acc[j][rr]);
    }
  }
}

// ---------------------------------------------------------------------------
// reduce partials -> kvbuf f32.
// ---------------------------------------------------------------------------
__global__ __launch_bounds__(256) void kv_reduce(const short* __restrict__ partial,
                                                 const float* __restrict__ beta,
                                                 float* __restrict__ kv) {
  const int m  = blockIdx.x % MD;
  const int bh = blockIdx.x / MD;
  const int h  = bh & 15;
  if (beta[h * MD + m] == 0.f) return;

  const int tid = threadIdx.x;
  const short* src = partial + (size_t)(bh * MD + m) * NCH * 4096;
  float* dst = kv + (size_t)(bh * MD + m) * 4096;
#pragma unroll
  for (int e0 = 0; e0 < 4096; e0 += 256) {
    float s = 0.f;
#pragma unroll
    for (int c = 0; c < NCH; ++c) s += bf2f(src[c * 4096 + e0 + tid]);
    dst[e0 + tid] = s;
  }
}

// ---------------------------------------------------------------------------
// attn: per (b,h,256 s-rows); kv staged bf16-transposed in LDS.
// ---------------------------------------------------------------------------
__global__ __launch_bounds__(256) void attn_kernel(const short* __restrict__ qkv,
                                                   const float* __restrict__ beta,
                                                   const float* __restrict__ kv,
                                                   short* __restrict__ attn) {
  const int bid  = blockIdx.x;
  const int bh   = bid >> 4;
  const int sblk = bid & 15;
  const int b    = bh >> 4, h = bh & 15;

  __shared__ short kvT[64][744];

  const int tid  = threadIdx.x;
  const int lane = tid & 63;
  const int w    = tid >> 6;
  const int g    = lane >> 4;
  const int r    = lane & 15;

  float betav[MD];
#pragma unroll
  for (int mm = 0; mm < MD; ++mm) betav[mm] = beta[h * MD + mm];

  {
    int am = 0;
#pragma unroll
    for (int mm = 0; mm < MD; ++mm) {
      if (betav[mm] != 0.f) {
        const float* src = kv + (size_t)(bh * MD + mm) * 4096;
        for (int e = tid; e < 4096; e += 256) {
          const int kd = e >> 6, dv = e & 63;
          kvT[dv][am * 64 + kd] = f2bf(src[e]);
        }
        ++am;
      }
    }
  }
  __syncthreads();

  const size_t qbase = (size_t)b * SEQ * 3072 + (size_t)h * 64;

#pragma unroll 1
  for (int st = 0; st < 4; ++st) {
    const int srow = sblk * 256 + w * 64 + st * 16 + r;
    const short* gq = qkv + qbase + (size_t)srow * 3072;
    short8 q0 = *(const short8*)(gq + g * 8);
    short8 q1 = *(const short8*)(gq + 32 + g * 8);
    float x[16];
#pragma unroll
    for (int q = 0; q < 8; ++q) {
      x[q]     = fminf(fmaxf(bf2f(q0[q]) * 0.125f, -1.f), 1.f);
      x[8 + q] = fminf(fmaxf(bf2f(q1[q]) * 0.125f, -1.f), 1.f);
    }
    float Tp[16], Tc[16];
#pragma unroll
    for (int q = 0; q < 16; ++q) { Tp[q] = 1.f; Tc[q] = x[q]; }
    f32x4 acc[4];
#pragma unroll
    for (int j = 0; j < 4; ++j) acc[j] = (f32x4){0.f, 0.f, 0.f, 0.f};

    int am = 0;
#pragma unroll
    for (int mt = 0; mt < MD; ++mt) {
      if (mt >= 2) {
#pragma unroll
        for (int q = 0; q < 16; ++q) {
          float Tn = 2.f * x[q] * Tc[q] - Tp[q];
          Tp[q] = Tc[q]; Tc[q] = Tn;
        }
      }
      if (betav[mt] != 0.f) {
        const float bm = betav[mt];
        short8 a0, a1;
        if (mt == 0) {
          const short one = f2bf(bm);
#pragma unroll
          for (int q = 0; q < 8; ++q) { a0[q] = one; a1[q] = one; }
        } else {
#pragma unroll
          for (int q = 0; q < 8; ++q) {
            a0[q] = f2bf(bm * Tc[q]);
            a1[q] = f2bf(bm * Tc[8 + q]);
          }
        }
#pragma unroll
        for (int j = 0; j < 4; ++j) {
          short8 b0 = *(const short8*)&kvT[j * 16 + r][am * 64 + g * 8];
          acc[j] = mfma16(a0, b0, acc[j]);
          short8 b1 = *(const short8*)&kvT[j * 16 + r][am * 64 + 32 + g * 8];
          acc[j] = mfma16(a1, b1, acc[j]);
        }
        ++am;
      }
    }

#pragma unroll
    for (int j = 0; j < 4; ++j) {
      const int col = h * 64 + j * 16 + r;
#pragma unroll
      for (int rr = 0; rr < 4; ++rr) {
        const int sr = sblk * 256 + w * 64 + st * 16 + g * 4 + rr;
        attn[(size_t)(b * SEQ + sr) * DMODEL + col] = f2bf(acc[j][rr]);
      }
    }
  }
}

// ---------------------------------------------------------------------------
extern "C" void kernel_launch(void* const* d_in, const int* in_sizes, int n_in,
                              void* d_out, int out_size, void* d_ws, size_t ws_size,
                              hipStream_t stream) {
  const float* x     = (const float*)d_in[0];
  const float* w_in  = (const float*)d_in[1];
  const float* w_out = (const float*)d_in[2];
  const float* beta  = (const float*)d_in[3];
  float* out = (float*)d_out;

  char* ws = (char*)d_ws;
  short* qkv     = (short*)ws;                    // 50,331,648 B
  float* kvbuf   = (float*)(ws + 50331648);       //  5,767,168 B
  short* w_inb   = (short*)(ws + 56098816);       //  6,291,456 B
  short* w_outb  = (short*)(ws + 62390272);       //  2,097,152 B
  char*  regionU = ws + 64487424;                 // xb / partial / attn union
  short* xb      = (short*)regionU;
  short* partial = (short*)regionU;
  short* attn    = (short*)regionU;

  const int Mrows = BATCH * SEQ;  // 8192

  // 0) pre-convert f32 -> bf16
  to_bf16<<<dim3(8192), dim3(256), 0, stream>>>(x,     xb,     2097152);
  to_bf16<<<dim3(3072), dim3(256), 0, stream>>>(w_in,  w_inb,   786432);
  to_bf16<<<dim3(1024), dim3(256), 0, stream>>>(w_out, w_outb,  262144);

  // 1) qkv = x @ w_in^T        (8192 x 3072 x 1024): 32 x 24 = 768 blocks
  gemm256<short><<<dim3((Mrows / 256) * (3 * DMODEL / 128)), dim3(512), 0, stream>>>(
      xb, w_inb, qkv, Mrows, 3 * DMODEL, DMODEL);

  // 2) kv partials over s-chunks, then reduce
  kv_partial<<<dim3(BATCH * NH * NCH), dim3(256), 0, stream>>>(qkv, beta, partial);
  kv_reduce<<<dim3(BATCH * NH * MD), dim3(256), 0, stream>>>(partial, beta, kvbuf);

  // 3) attn = sum_m beta_m T_m(q) @ kv_m
  attn_kernel<<<dim3(32 * 16), dim3(256), 0, stream>>>(qkv, beta, kvbuf, attn);

  // 4) out = attn @ w_out^T    (8192 x 1024 x 1024): 32 x 8 = 256 blocks
  gemm256<float><<<dim3((Mrows / 256) * (DMODEL / 128)), dim3(512), 0, stream>>>(
      attn, w_outb, out, Mrows, DMODEL, DMODEL);
}

// Round 7
// 169.800 us; speedup vs baseline: 1.8715x; 1.0710x over previous
//
#include <hip/hip_runtime.h>
#include <hip/hip_bf16.h>

// ---------------------------------------------------------------------------
// CollapsedPBFA: x->(qkv GEMM)->cheb-kernelized linear attention->out GEMM
// R7: GEMM K-loop restructured: 3-buffer LDS rotation, ONE barrier + counted
//     vmcnt(6) per K-tile, quadrant-phased frag reads overlapping MFMA.
//     (R6 had 3 barriers/tile -> read/MFMA lockstep, MfmaUtil stuck at 28%.)
//     kv_partial / kv_reduce / attn unchanged (passed, absmax 32).
// ---------------------------------------------------------------------------

#define SEQ    4096
#define BATCH  2
#define DMODEL 1024
#define NH     16
#define DH     64
#define MD     11
#define NCH    8
#define CHUNK  512   // SEQ / NCH

typedef __attribute__((ext_vector_type(8)))  short  short8;
typedef __attribute__((ext_vector_type(4)))  short  s16x4;
typedef __attribute__((ext_vector_type(8)))  __bf16 bf16x8;
typedef __attribute__((ext_vector_type(4)))  float  f32x4;

__device__ __forceinline__ short f2bf(float f) {
  union { float f; unsigned u; } c; c.f = f;
  unsigned r = c.u + 0x7FFFu + ((c.u >> 16) & 1u);
  return (short)(r >> 16);
}
__device__ __forceinline__ float bf2f(short h) {
  union { unsigned u; float f; } c; c.u = ((unsigned)(unsigned short)h) << 16;
  return c.f;
}

__device__ __forceinline__ f32x4 mfma16(short8 a, short8 b, f32x4 c) {
  return __builtin_amdgcn_mfma_f32_16x16x32_bf16(
      __builtin_bit_cast(bf16x8, a), __builtin_bit_cast(bf16x8, b), c, 0, 0, 0);
}

typedef const __attribute__((address_space(1))) void* gvp;
typedef __attribute__((address_space(3))) void* lvp;
// Async global->LDS, 16B per lane: lane i lands at (uniform dst) + 16*i.
__device__ __forceinline__ void gload16(const void* g, void* l) {
  __builtin_amdgcn_global_load_lds((gvp)g, (lvp)l, 16, 0, 0);
}

// ---------------------------------------------------------------------------
// f32 -> bf16 elementwise convert (vectorized).
// ---------------------------------------------------------------------------
__global__ __launch_bounds__(256) void to_bf16(const float* __restrict__ src,
                                               short* __restrict__ dst, int n4) {
  int i = blockIdx.x * 256 + threadIdx.x;
  if (i < n4) {
    f32x4 v = ((const f32x4*)src)[i];
    s16x4 o;
#pragma unroll
    for (int q = 0; q < 4; ++q) o[q] = f2bf(v[q]);
    ((s16x4*)dst)[i] = o;
  }
}

// ---------------------------------------------------------------------------
// GEMM: C[M][N] = A[M][K] * B[N][K]^T, A/B bf16.
// Tile 256x128, BK=64, 512 threads = 8 waves (WM=4 x WN=2), per-wave 64x64.
// 3-buffer LDS rotation (144KB), 1 barrier + counted vmcnt(6) per K-tile,
// quadrant-phased frag reads overlap MFMA, XOR chunk swizzle (both-sides).
// Requires: M%256==0, N%128==0, K%64==0, NT>=2, grid%8==0.
// ---------------------------------------------------------------------------
template <typename SC>
__global__ __launch_bounds__(512) void gemm256(const short* __restrict__ A,
                                               const short* __restrict__ B,
                                               SC* __restrict__ C,
                                               int M, int N, int K) {
  // per buf: A 256x64 (16384 sh) + B 128x64 (8192 sh) = 24576 sh; 3 bufs.
  __shared__ short lds[73728];

  const int tid  = threadIdx.x;
  const int lane = tid & 63;
  const int w    = tid >> 6;        // 0..7
  const int wm   = w >> 1;          // 0..3
  const int wn   = w & 1;           // 0..1
  const int g    = lane >> 4;       // 0..3
  const int r    = lane & 15;       // 0..15

  const int nbn = N >> 7;
  int bid = blockIdx.x;
  {  // bijective XCD swizzle (gridDim.x % 8 == 0 for our shapes)
    const int cpx = gridDim.x >> 3;
    bid = (bid & 7) * cpx + (bid >> 3);
  }
  const int brow = (bid / nbn) << 8;
  const int bcol = (bid % nbn) << 7;
  const int NT   = K >> 6;

  // staging lane geometry: per gload16 issue a wave covers 8 rows x 64 cols.
  const int lr    = lane >> 3;
  const int lc    = lane & 7;
  const int swz_w = ((w * 8 + lr) >> 1) & 7;
  const int cgs   = (lc ^ swz_w) * 8;      // pre-swizzled global col (shorts)
  const int swz_r = (r >> 1) & 7;          // read-side swizzle

  f32x4 acc[4][4];
#pragma unroll
  for (int mi = 0; mi < 4; ++mi)
#pragma unroll
    for (int ni = 0; ni < 4; ++ni) acc[mi][ni] = (f32x4){0.f, 0.f, 0.f, 0.f};

  auto STAGE = [&](int buf, int t) {
    const int k0 = t << 6;
    short* ab = &lds[buf * 24576];
    short* bb = &lds[buf * 24576 + 16384];
#pragma unroll
    for (int i = 0; i < 4; ++i) {
      const short* ga = A + (size_t)(brow + i * 64 + w * 8 + lr) * K + k0 + cgs;
      gload16(ga, ab + (i * 64 + w * 8) * 64);
    }
#pragma unroll
    for (int i = 0; i < 2; ++i) {
      const short* gb = B + (size_t)(bcol + i * 64 + w * 8 + lr) * K + k0 + cgs;
      gload16(gb, bb + (i * 64 + w * 8) * 64);
    }
  };

  auto AF = [&](const short* ab, int mi, int ks) -> short8 {
    return *(const short8*)(ab + (wm * 64 + mi * 16 + r) * 64 +
                            (((ks * 4 + g) ^ swz_r) * 8));
  };
  auto BF = [&](const short* bb, int ni, int ks) -> short8 {
    return *(const short8*)(bb + (wn * 64 + ni * 16 + r) * 64 +
                            (((ks * 4 + g) ^ swz_r) * 8));
  };

  // ---- prologue: 2 tiles in flight, prefetch quadrant-0 frags of tile 0 ----
  STAGE(0, 0);
  STAGE(1, 1);
  asm volatile("s_waitcnt vmcnt(6)\n\ts_barrier" ::: "memory");

  short8 a0[2][2], b0[2][2], a2[2][2], b2[2][2];
  {
    const short* ab = &lds[0];
    const short* bb = &lds[16384];
#pragma unroll
    for (int mi = 0; mi < 2; ++mi)
#pragma unroll
      for (int ks = 0; ks < 2; ++ks) a0[mi][ks] = AF(ab, mi, ks);
#pragma unroll
    for (int ni = 0; ni < 2; ++ni)
#pragma unroll
      for (int ks = 0; ks < 2; ++ks) b0[ni][ks] = BF(bb, ni, ks);
  }

  int cur = 0, nxt = 1, stg = 2;
  for (int kt = 0; kt < NT; ++kt) {
    const short* ab = &lds[cur * 24576];
    const short* bb = &lds[cur * 24576 + 16384];

    // stage tile kt+2 into the buffer freed one iteration ago
    if (kt + 2 < NT) STAGE(stg, kt + 2);

    // phase reads b2 (hidden under q0 MFMAs)
#pragma unroll
    for (int ni = 0; ni < 2; ++ni)
#pragma unroll
      for (int ks = 0; ks < 2; ++ks) b2[ni][ks] = BF(bb, ni + 2, ks);

    __builtin_amdgcn_s_setprio(1);
#pragma unroll
    for (int mi = 0; mi < 2; ++mi)
#pragma unroll
      for (int ni = 0; ni < 2; ++ni) {
        acc[mi][ni] = mfma16(a0[mi][0], b0[ni][0], acc[mi][ni]);
        acc[mi][ni] = mfma16(a0[mi][1], b0[ni][1], acc[mi][ni]);
      }
    __builtin_amdgcn_s_setprio(0);

    // phase reads a2 (hidden under q1 MFMAs)
#pragma unroll
    for (int mi = 0; mi < 2; ++mi)
#pragma unroll
      for (int ks = 0; ks < 2; ++ks) a2[mi][ks] = AF(ab, mi + 2, ks);

    __builtin_amdgcn_s_setprio(1);
#pragma unroll
    for (int mi = 0; mi < 2; ++mi)
#pragma unroll
      for (int ni = 0; ni < 2; ++ni) {
        acc[mi][ni + 2] = mfma16(a0[mi][0], b2[ni][0], acc[mi][ni + 2]);
        acc[mi][ni + 2] = mfma16(a0[mi][1], b2[ni][1], acc[mi][ni + 2]);
      }
#pragma unroll
    for (int mi = 0; mi < 2; ++mi)
#pragma unroll
      for (int ni = 0; ni < 2; ++ni) {
        acc[mi + 2][ni + 2] = mfma16(a2[mi][0], b2[ni][0], acc[mi + 2][ni + 2]);
        acc[mi + 2][ni + 2] = mfma16(a2[mi][1], b2[ni][1], acc[mi + 2][ni + 2]);
      }
#pragma unroll
    for (int mi = 0; mi < 2; ++mi)
#pragma unroll
      for (int ni = 0; ni < 2; ++ni) {
        acc[mi + 2][ni] = mfma16(a2[mi][0], b0[ni][0], acc[mi + 2][ni]);
        acc[mi + 2][ni] = mfma16(a2[mi][1], b0[ni][1], acc[mi + 2][ni]);
      }
    __builtin_amdgcn_s_setprio(0);

    // tile boundary: ensure tile kt+1 landed, sync, prefetch its q0 frags
    if (kt + 1 < NT) {
      if (kt + 2 < NT) asm volatile("s_waitcnt vmcnt(6)\n\ts_barrier" ::: "memory");
      else             asm volatile("s_waitcnt vmcnt(0)\n\ts_barrier" ::: "memory");
      const short* an = &lds[nxt * 24576];
      const short* bn = &lds[nxt * 24576 + 16384];
#pragma unroll
      for (int mi = 0; mi < 2; ++mi)
#pragma unroll
        for (int ks = 0; ks < 2; ++ks) a0[mi][ks] = AF(an, mi, ks);
#pragma unroll
      for (int ni = 0; ni < 2; ++ni)
#pragma unroll
        for (int ks = 0; ks < 2; ++ks) b0[ni][ks] = BF(bn, ni, ks);
    }

    const int t = cur; cur = nxt; nxt = stg; stg = t;
  }

#pragma unroll
  for (int mi = 0; mi < 4; ++mi) {
    const int row0 = brow + wm * 64 + mi * 16 + g * 4;
#pragma unroll
    for (int ni = 0; ni < 4; ++ni) {
      const int col = bcol + wn * 64 + ni * 16 + r;
#pragma unroll
      for (int rr = 0; rr < 4; ++rr) {
        float v = acc[mi][ni][rr];
        if constexpr (sizeof(SC) == 2) C[(size_t)(row0 + rr) * N + col] = f2bf(v);
        else                           C[(size_t)(row0 + rr) * N + col] = v;
      }
    }
  }
}

// ---------------------------------------------------------------------------
// kv partial: block = (bh, chunk of 512 s-rows). Stage k~/v transposed into
// chunk-resident LDS once, loop active m over the resident tile.
// ---------------------------------------------------------------------------
__global__ __launch_bounds__(256) void kv_partial(const short* __restrict__ qkv,
                                                  const float* __restrict__ beta,
                                                  short* __restrict__ partial) {
  const int bh = blockIdx.x / NCH;
  const int ch = blockIdx.x % NCH;
  const int b  = bh >> 4, h = bh & 15;

  __shared__ short kT[64][522];   // [kd][s], stride 261 dw
  __shared__ short vT[64][522];   // [dv][s]

  const int tid  = threadIdx.x;
  const int lane = tid & 63;
  const int w    = tid >> 6;
  const int g    = lane >> 4;
  const int r    = lane & 15;

  const int srl  = tid >> 2;
  const int part = tid & 3;
  const size_t base = (size_t)b * SEQ * 3072 + (size_t)(ch * CHUNK) * 3072;
  const int kcol = DMODEL     + h * 64 + part * 16;
  const int vcol = 2 * DMODEL + h * 64 + part * 16;

#pragma unroll
  for (int ss = 0; ss < CHUNK; ss += 64) {
    const short* gk = qkv + base + (size_t)(ss + srl) * 3072 + kcol;
    const short* gv = qkv + base + (size_t)(ss + srl) * 3072 + vcol;
    short8 k0 = *(const short8*)gk;
    short8 k1 = *(const short8*)(gk + 8);
    short8 v0 = *(const short8*)gv;
    short8 v1 = *(const short8*)(gv + 8);
    const int sidx = ss + srl;
#pragma unroll
    for (int q = 0; q < 8; ++q) {
      kT[part * 16 + q][sidx]     = f2bf(fminf(fmaxf(bf2f(k0[q]) * 0.125f, -1.f), 1.f));
      kT[part * 16 + 8 + q][sidx] = f2bf(fminf(fmaxf(bf2f(k1[q]) * 0.125f, -1.f), 1.f));
      vT[part * 16 + q][sidx]     = v0[q];
      vT[part * 16 + 8 + q][sidx] = v1[q];
    }
  }
  __syncthreads();

  for (int m = 0; m < MD; ++m) {
    if (beta[h * MD + m] == 0.f) continue;

    f32x4 acc[4];
#pragma unroll
    for (int j = 0; j < 4; ++j) acc[j] = (f32x4){0.f, 0.f, 0.f, 0.f};

#pragma unroll 1
    for (int kt = 0; kt < CHUNK / 32; ++kt) {
      const int s0 = kt * 32 + g * 8;
      short8 af;
      if (m == 0) {
#pragma unroll
        for (int q = 0; q < 8; ++q) af[q] = (short)0x3F80;
      } else {
        short8 xs = *(const short8*)&kT[w * 16 + r][s0];
        float Tp[8], Tc[8];
#pragma unroll
        for (int q = 0; q < 8; ++q) { float xv = bf2f(xs[q]); Tp[q] = 1.f; Tc[q] = xv; }
        for (int mm = 1; mm < m; ++mm) {
#pragma unroll
          for (int q = 0; q < 8; ++q) {
            float xv = bf2f(xs[q]);
            float Tn = 2.f * xv * Tc[q] - Tp[q];
            Tp[q] = Tc[q]; Tc[q] = Tn;
          }
        }
#pragma unroll
        for (int q = 0; q < 8; ++q) af[q] = f2bf(Tc[q]);
      }
#pragma unroll
      for (int j = 0; j < 4; ++j) {
        short8 bfg = *(const short8*)&vT[j * 16 + r][s0];
        acc[j] = mfma16(af, bfg, acc[j]);
      }
    }

    short* po = partial + ((size_t)(bh * MD + m) * NCH + ch) * 4096;
#pragma unroll
    for (int j = 0; j < 4; ++j) {
      const int kd = w * 16 + g * 4;
      const int dv = j * 16 + r;
#pragma unroll
      for (int rr = 0; rr < 4; ++rr) po[(size_t)(kd + rr) * 64 + dv] = f2bf(acc[j][rr]);
    }
  }
}

// ---------------------------------------------------------------------------
// reduce partials -> kvbuf f32.
// ---------------------------------------------------------------------------
__global__ __launch_bounds__(256) void kv_reduce(const short* __restrict__ partial,
                                                 const float* __restrict__ beta,
                                                 float* __restrict__ kv) {
  const int m  = blockIdx.x % MD;
  const int bh = blockIdx.x / MD;
  const int h  = bh & 15;
  if (beta[h * MD + m] == 0.f) return;

  const int tid = threadIdx.x;
  const short* src = partial + (size_t)(bh * MD + m) * NCH * 4096;
  float* dst = kv + (size_t)(bh * MD + m) * 4096;
#pragma unroll
  for (int e0 = 0; e0 < 4096; e0 += 256) {
    float s = 0.f;
#pragma unroll
    for (int c = 0; c < NCH; ++c) s += bf2f(src[c * 4096 + e0 + tid]);
    dst[e0 + tid] = s;
  }
}

// ---------------------------------------------------------------------------
// attn: per (b,h,256 s-rows); kv staged bf16-transposed in LDS.
// ---------------------------------------------------------------------------
__global__ __launch_bounds__(256) void attn_kernel(const short* __restrict__ qkv,
                                                   const float* __restrict__ beta,
                                                   const float* __restrict__ kv,
                                                   short* __restrict__ attn) {
  const int bid  = blockIdx.x;
  const int bh   = bid >> 4;
  const int sblk = bid & 15;
  const int b    = bh >> 4, h = bh & 15;

  __shared__ short kvT[64][744];

  const int tid  = threadIdx.x;
  const int lane = tid & 63;
  const int w    = tid >> 6;
  const int g    = lane >> 4;
  const int r    = lane & 15;

  float betav[MD];
#pragma unroll
  for (int mm = 0; mm < MD; ++mm) betav[mm] = beta[h * MD + mm];

  {
    int am = 0;
#pragma unroll
    for (int mm = 0; mm < MD; ++mm) {
      if (betav[mm] != 0.f) {
        const float* src = kv + (size_t)(bh * MD + mm) * 4096;
        for (int e = tid; e < 4096; e += 256) {
          const int kd = e >> 6, dv = e & 63;
          kvT[dv][am * 64 + kd] = f2bf(src[e]);
        }
        ++am;
      }
    }
  }
  __syncthreads();

  const size_t qbase = (size_t)b * SEQ * 3072 + (size_t)h * 64;

#pragma unroll 1
  for (int st = 0; st < 4; ++st) {
    const int srow = sblk * 256 + w * 64 + st * 16 + r;
    const short* gq = qkv + qbase + (size_t)srow * 3072;
    short8 q0 = *(const short8*)(gq + g * 8);
    short8 q1 = *(const short8*)(gq + 32 + g * 8);
    float x[16];
#pragma unroll
    for (int q = 0; q < 8; ++q) {
      x[q]     = fminf(fmaxf(bf2f(q0[q]) * 0.125f, -1.f), 1.f);
      x[8 + q] = fminf(fmaxf(bf2f(q1[q]) * 0.125f, -1.f), 1.f);
    }
    float Tp[16], Tc[16];
#pragma unroll
    for (int q = 0; q < 16; ++q) { Tp[q] = 1.f; Tc[q] = x[q]; }
    f32x4 acc[4];
#pragma unroll
    for (int j = 0; j < 4; ++j) acc[j] = (f32x4){0.f, 0.f, 0.f, 0.f};

    int am = 0;
#pragma unroll
    for (int mt = 0; mt < MD; ++mt) {
      if (mt >= 2) {
#pragma unroll
        for (int q = 0; q < 16; ++q) {
          float Tn = 2.f * x[q] * Tc[q] - Tp[q];
          Tp[q] = Tc[q]; Tc[q] = Tn;
        }
      }
      if (betav[mt] != 0.f) {
        const float bm = betav[mt];
        short8 a0, a1;
        if (mt == 0) {
          const short one = f2bf(bm);
#pragma unroll
          for (int q = 0; q < 8; ++q) { a0[q] = one; a1[q] = one; }
        } else {
#pragma unroll
          for (int q = 0; q < 8; ++q) {
            a0[q] = f2bf(bm * Tc[q]);
            a1[q] = f2bf(bm * Tc[8 + q]);
          }
        }
#pragma unroll
        for (int j = 0; j < 4; ++j) {
          short8 b0 = *(const short8*)&kvT[j * 16 + r][am * 64 + g * 8];
          acc[j] = mfma16(a0, b0, acc[j]);
          short8 b1 = *(const short8*)&kvT[j * 16 + r][am * 64 + 32 + g * 8];
          acc[j] = mfma16(a1, b1, acc[j]);
        }
        ++am;
      }
    }

#pragma unroll
    for (int j = 0; j < 4; ++j) {
      const int col = h * 64 + j * 16 + r;
#pragma unroll
      for (int rr = 0; rr < 4; ++rr) {
        const int sr = sblk * 256 + w * 64 + st * 16 + g * 4 + rr;
        attn[(size_t)(b * SEQ + sr) * DMODEL + col] = f2bf(acc[j][rr]);
      }
    }
  }
}

// ---------------------------------------------------------------------------
extern "C" void kernel_launch(void* const* d_in, const int* in_sizes, int n_in,
                              void* d_out, int out_size, void* d_ws, size_t ws_size,
                              hipStream_t stream) {
  const float* x     = (const float*)d_in[0];
  const float* w_in  = (const float*)d_in[1];
  const float* w_out = (const float*)d_in[2];
  const float* beta  = (const float*)d_in[3];
  float* out = (float*)d_out;

  char* ws = (char*)d_ws;
  short* qkv     = (short*)ws;                    // 50,331,648 B
  float* kvbuf   = (float*)(ws + 50331648);       //  5,767,168 B
  short* w_inb   = (short*)(ws + 56098816);       //  6,291,456 B
  short* w_outb  = (short*)(ws + 62390272);       //  2,097,152 B
  char*  regionU = ws + 64487424;                 // xb / partial / attn union
  short* xb      = (short*)regionU;
  short* partial = (short*)regionU;
  short* attn    = (short*)regionU;

  const int Mrows = BATCH * SEQ;  // 8192

  // 0) pre-convert f32 -> bf16
  to_bf16<<<dim3(8192), dim3(256), 0, stream>>>(x,     xb,     2097152);
  to_bf16<<<dim3(3072), dim3(256), 0, stream>>>(w_in,  w_inb,   786432);
  to_bf16<<<dim3(1024), dim3(256), 0, stream>>>(w_out, w_outb,  262144);

  // 1) qkv = x @ w_in^T        (8192 x 3072 x 1024): 32 x 24 = 768 blocks
  gemm256<short><<<dim3((Mrows / 256) * (3 * DMODEL / 128)), dim3(512), 0, stream>>>(
      xb, w_inb, qkv, Mrows, 3 * DMODEL, DMODEL);

  // 2) kv partials over s-chunks, then reduce
  kv_partial<<<dim3(BATCH * NH * NCH), dim3(256), 0, stream>>>(qkv, beta, partial);
  kv_reduce<<<dim3(BATCH * NH * MD), dim3(256), 0, stream>>>(partial, beta, kvbuf);

  // 3) attn = sum_m beta_m T_m(q) @ kv_m
  attn_kernel<<<dim3(32 * 16), dim3(256), 0, stream>>>(qkv, beta, kvbuf, attn);

  // 4) out = attn @ w_out^T    (8192 x 1024 x 1024): 32 x 8 = 256 blocks
  gemm256<float><<<dim3((Mrows / 256) * (DMODEL / 128)), dim3(512), 0, stream>>>(
      attn, w_outb, out, Mrows, DMODEL, DMODEL);
}